// Round 22
// baseline (370.456 us; speedup 1.0000x reference)
//
#include <hip/hip_runtime.h>
#include <hip/hip_bf16.h>

typedef __hip_bfloat16 bf16;
#define DEVI __device__ __forceinline__

// Problem constants
static constexpr int BATCH = 8;
static constexpr int NPT   = 2048;
static constexpr int DMID  = 64;
static constexpr int DEMB  = 256;
static constexpr int NSA   = 4;
static constexpr long STRD = (long)DEMB * NPT;  // 524288
static constexpr long NN   = (long)NPT * NPT;   // 4194304

typedef __attribute__((ext_vector_type(4))) float f32x4;
typedef __attribute__((ext_vector_type(8))) short bf16x8v;

DEVI f32x4 MFMA16(bf16x8v a, bf16x8v b, f32x4 c) {
  return __builtin_amdgcn_mfma_f32_16x16x32_bf16(a, b, c, 0, 0, 0);
}

DEVI void gload16(const bf16* g, bf16* l) {
  __builtin_amdgcn_global_load_lds(
      (const __attribute__((address_space(1))) void*)g,
      (__attribute__((address_space(3))) void*)l, 16, 0, 0);
}

DEVI float waveReduceSum(float v) {
#pragma unroll
  for (int o = 32; o > 0; o >>= 1) v += __shfl_down(v, o, 64);
  return v;
}
DEVI float blockReduceSum(float v) {
  __shared__ float sm[4];
  int lane = threadIdx.x & 63, wid = threadIdx.x >> 6;
  __syncthreads();
  v = waveReduceSum(v);
  if (lane == 0) sm[wid] = v;
  __syncthreads();
  return sm[0] + sm[1] + sm[2] + sm[3];
}

// ---- fused weight converts: W2 | Wv ----
__global__ void k_cvtall(const float* __restrict__ w2, const float* __restrict__ wv,
                         bf16* __restrict__ W2b, bf16* __restrict__ WVb) {
  int idx = blockIdx.x * 256 + threadIdx.x;
  if (idx < DEMB * DMID) {
    W2b[idx] = __float2bfloat16(w2[idx]);
  } else {
    int i = idx - DEMB * DMID;
    if (i < NSA * DEMB * DEMB) WVb[i] = __float2bfloat16(wv[i]);
  }
}

// ---- WkqT[l][c'][c] = sum_j Wk[l][j][c] * Wq[l][j][c']  (bf16 out) ----
// grid (256, NSA), 256 threads; thread c, block c'. Wk reads coalesced.
__global__ __launch_bounds__(256) void k_wkq(const float* __restrict__ wq,
                                             const float* __restrict__ wk,
                                             bf16* __restrict__ wkqT) {
  int cp = blockIdx.x;
  int l = blockIdx.y;
  int c = threadIdx.x;
  __shared__ float q[256];
  q[c] = wq[((long)l * 256 + c) * 256 + cp];  // Wq[l][j=c][cp]
  __syncthreads();
  const float* wkl = wk + (long)l * 256 * 256;
  float s = 0.f;
  for (int j = 0; j < 256; ++j) s += wkl[j * 256 + c] * q[j];
  wkqT[((long)l * 256 + cp) * 256 + c] = __float2bfloat16(s);
}

// ---- fused conv1 + BN1 partial stats ----
__global__ __launch_bounds__(256) void k_conv1bn(const float* __restrict__ x,
                                                 const float* __restrict__ w1,
                                                 const float* __restrict__ b1,
                                                 float* __restrict__ h1t,
                                                 float* __restrict__ pS, float* __restrict__ pS2) {
  int c = threadIdx.x & 63, rg = threadIdx.x >> 6;
  long r0 = (long)blockIdx.x * 128 + rg * 32;
  float w0 = w1[c * 3], w1v = w1[c * 3 + 1], w2v = w1[c * 3 + 2], bb = b1[c];
  float s = 0.f, s2 = 0.f;
  for (int i = 0; i < 32; ++i) {
    long r = r0 + i;
    const float* xp = x + r * 3;
    float acc = bb;
    acc += xp[0] * w0;
    acc += xp[1] * w1v;
    acc += xp[2] * w2v;
    h1t[r * 64 + c] = acc;
    s += acc; s2 += acc * acc;
  }
  __shared__ float smS[256], smS2[256];
  smS[threadIdx.x] = s; smS2[threadIdx.x] = s2;
  __syncthreads();
  if (threadIdx.x < 64) {
    float a = 0.f, b = 0.f;
#pragma unroll
    for (int g = 0; g < 4; ++g) { a += smS[g * 64 + c]; b += smS2[g * 64 + c]; }
    pS[blockIdx.x * 64 + c] = a;
    pS2[blockIdx.x * 64 + c] = b;
  }
}
__global__ void k_bn1b(const float* __restrict__ pS, const float* __restrict__ pS2,
                       const float* __restrict__ g, const float* __restrict__ be,
                       float* __restrict__ sa, float* __restrict__ sb) {
  int c = threadIdx.x;
  if (c >= 64) return;
  float s = 0.f, s2 = 0.f;
  for (int i = 0; i < 128; ++i) { s += pS[i * 64 + c]; s2 += pS2[i * 64 + c]; }
  const float inv = 1.0f / (BATCH * NPT);
  float m = s * inv, var = s2 * inv - m * m;
  float A = rsqrtf(var + 1e-5f) * g[c];
  sa[c] = A; sb[c] = be[c] - m * A;
}
// BN1 apply + ReLU (vectorized x4)
__global__ void k_bn1apply(const float* __restrict__ h, const float* __restrict__ sa,
                           const float* __restrict__ sb, bf16* __restrict__ o) {
  long i = ((long)blockIdx.x * 256 + threadIdx.x) * 4;
  int c = (int)(i & 63);
  float4 v4 = *(const float4*)(h + i);
  float4 a4 = *(const float4*)(sa + c);
  float4 b4 = *(const float4*)(sb + c);
  float r0 = fmaf(v4.x, a4.x, b4.x); r0 = r0 > 0.f ? r0 : 0.f;
  float r1 = fmaf(v4.y, a4.y, b4.y); r1 = r1 > 0.f ? r1 : 0.f;
  float r2 = fmaf(v4.z, a4.z, b4.z); r2 = r2 > 0.f ? r2 : 0.f;
  float r3 = fmaf(v4.w, a4.w, b4.w); r3 = r3 > 0.f ? r3 : 0.f;
  bf16 hb[4] = {__float2bfloat16(r0), __float2bfloat16(r1),
                __float2bfloat16(r2), __float2bfloat16(r3)};
  *(uint2*)(o + i) = *(uint2*)hb;
}

// ---- BN2 combine (partials from conv2 epilogue) ----
__global__ void k_bn2b(const float* __restrict__ pA, const float* __restrict__ pB,
                       const float* __restrict__ g, const float* __restrict__ be,
                       float* __restrict__ sa, float* __restrict__ sb) {
  int c = threadIdx.x;  // 256 threads
  float s = 0.f, s2 = 0.f;
  for (int i = 0; i < 128; ++i) { s += pA[i * DEMB + c]; s2 += pB[i * DEMB + c]; }
  const float inv = 1.0f / (BATCH * NPT);
  float m = s * inv, var = s2 * inv - m * m;
  float A = rsqrtf(var + 1e-5f) * g[c];
  sa[c] = A; sb[c] = be[c] - m * A;
}
// BN2 apply + ReLU: write Hn (f32) and Htb (bf16), vectorized x4
__global__ void k_bnapply2(float* __restrict__ hn, bf16* __restrict__ htb,
                           const float* __restrict__ sa, const float* __restrict__ sb) {
  long i = ((long)blockIdx.x * 256 + threadIdx.x) * 4;
  int c = (int)(i & (DEMB - 1));
  float4 v4 = *(const float4*)(hn + i);
  float4 a4 = *(const float4*)(sa + c);
  float4 b4 = *(const float4*)(sb + c);
  float r0 = fmaf(v4.x, a4.x, b4.x); r0 = r0 > 0.f ? r0 : 0.f;
  float r1 = fmaf(v4.y, a4.y, b4.y); r1 = r1 > 0.f ? r1 : 0.f;
  float r2 = fmaf(v4.z, a4.z, b4.z); r2 = r2 > 0.f ? r2 : 0.f;
  float r3 = fmaf(v4.w, a4.w, b4.w); r3 = r3 > 0.f ? r3 : 0.f;
  *(float4*)(hn + i) = float4{r0, r1, r2, r3};
  bf16 hb[4] = {__float2bfloat16(r0), __float2bfloat16(r1),
                __float2bfloat16(r2), __float2bfloat16(r3)};
  *(uint2*)(htb + i) = *(uint2*)hb;
}

// ---- MFMA GEMM (conv2): C f32 = A.B^T + bias[col], fused BN partials ----
__global__ __launch_bounds__(256) void k_mgemm2(
    const bf16* __restrict__ A, int ldA,
    const bf16* __restrict__ B, int ldB,
    float* __restrict__ C, int ldC,
    int K, const float* __restrict__ bias,
    float* __restrict__ PMo, float* __restrict__ PSo) {
  __shared__ __align__(16) bf16 sA[128 * 64];
  __shared__ __align__(16) bf16 sB[128 * 64];
  __shared__ float smx[4][64], ssx[4][64];
  const int bx = blockIdx.x, by = blockIdx.y;
  const int bm = by * 128, bn = bx * 128;
  const int tid = threadIdx.x;
  const int lane = tid & 63, wv = tid >> 6;
  const int wr = (wv >> 1) * 64, wc = (wv & 1) * 64;
  f32x4 acc[4][4] = {};

  for (int k0 = 0; k0 < K; k0 += 64) {
#pragma unroll
    for (int i = 0; i < 4; ++i) {
      int c = i * 256 + tid;
      int row = c >> 3, g = c & 7;
      int gs = (g ^ (row & 7)) * 8;
      gload16(A + (long)(bm + row) * ldA + k0 + gs, sA + c * 8);
      gload16(B + (long)(bn + row) * ldB + k0 + gs, sB + c * 8);
    }
    __syncthreads();
    bf16x8v af[4][2], bfr[4][2];
#pragma unroll
    for (int mi = 0; mi < 4; ++mi)
#pragma unroll
      for (int ks = 0; ks < 2; ++ks) {
        int rA = wr + mi * 16 + (lane & 15);
        int rB = wc + mi * 16 + (lane & 15);
        int g = ks * 4 + (lane >> 4);
        af[mi][ks]  = *(const bf16x8v*)&sA[rA * 64 + ((g ^ (rA & 7)) * 8)];
        bfr[mi][ks] = *(const bf16x8v*)&sB[rB * 64 + ((g ^ (rB & 7)) * 8)];
      }
#pragma unroll
    for (int ks = 0; ks < 2; ++ks)
#pragma unroll
      for (int mi = 0; mi < 4; ++mi)
#pragma unroll
        for (int ni = 0; ni < 4; ++ni)
          acc[mi][ni] = MFMA16(af[mi][ks], bfr[ni][ks], acc[mi][ni]);
    __syncthreads();
  }

  const int rb = (lane >> 4) * 4, cb = lane & 15;
  float st_s[4] = {}, st_q[4] = {};
#pragma unroll
  for (int mi = 0; mi < 4; ++mi)
#pragma unroll
    for (int ni = 0; ni < 4; ++ni) {
      int r0 = bm + wr + mi * 16 + rb, c0 = bn + wc + ni * 16 + cb;
      float badd = bias[c0];
#pragma unroll
      for (int k = 0; k < 4; ++k) {
        int r = r0 + k;
        float v = acc[mi][ni][k] + badd;
        C[(long)r * ldC + c0] = v;
        st_s[ni] += v;
        st_q[ni] += v * v;
      }
    }

#pragma unroll
  for (int ni = 0; ni < 4; ++ni) {
#pragma unroll
    for (int off = 16; off <= 32; off <<= 1) {
      st_s[ni] += __shfl_xor(st_s[ni], off, 64);
      st_q[ni] += __shfl_xor(st_q[ni], off, 64);
    }
  }
  __syncthreads();
  if (lane < 16) {
#pragma unroll
    for (int ni = 0; ni < 4; ++ni) {
      smx[wv][ni * 16 + lane] = st_s[ni];
      ssx[wv][ni * 16 + lane] = st_q[ni];
    }
  }
  __syncthreads();
  if (tid < 128) {
    int half = tid >> 6, c64 = tid & 63;
    float S = smx[half][c64] + smx[half + 2][c64];
    float Q = ssx[half][c64] + ssx[half + 2][c64];
    int col = bn + half * 64 + c64;
    PMo[by * DEMB + col] = S;
    PSo[by * DEMB + col] = Q;
  }
}

// ---- M projection: M[z][n][c'] = Htb[z] . WkqT^T  (256 blocks) ----
__global__ __launch_bounds__(256) void k_m(
    const bf16* __restrict__ Htb, const bf16* __restrict__ WkqT, bf16* __restrict__ M) {
  __shared__ __align__(16) bf16 sA[128 * 64];
  __shared__ __align__(16) bf16 sB[128 * 64];
  int s = blockIdx.x;
  int z = s & 7, t = s >> 3;
  const bf16* A = Htb + (long)z * STRD;
  const bf16* B = WkqT;
  bf16* C = M + (long)z * STRD;
  const int bm = (t >> 1) * 128, bn = (t & 1) * 128;
  const int tid = threadIdx.x;
  const int lane = tid & 63, wv = tid >> 6;
  const int wr = (wv >> 1) * 64, wc = (wv & 1) * 64;
  f32x4 acc[4][4] = {};

  for (int k0 = 0; k0 < DEMB; k0 += 64) {
#pragma unroll
    for (int i = 0; i < 4; ++i) {
      int c = i * 256 + tid;
      int row = c >> 3, g = c & 7;
      int gs = (g ^ (row & 7)) * 8;
      gload16(A + (long)(bm + row) * DEMB + k0 + gs, sA + c * 8);
      gload16(B + (long)(bn + row) * DEMB + k0 + gs, sB + c * 8);
    }
    __syncthreads();
    bf16x8v af[4][2], bfr[4][2];
#pragma unroll
    for (int mi = 0; mi < 4; ++mi)
#pragma unroll
      for (int ks = 0; ks < 2; ++ks) {
        int rA = wr + mi * 16 + (lane & 15);
        int rB = wc + mi * 16 + (lane & 15);
        int g = ks * 4 + (lane >> 4);
        af[mi][ks]  = *(const bf16x8v*)&sA[rA * 64 + ((g ^ (rA & 7)) * 8)];
        bfr[mi][ks] = *(const bf16x8v*)&sB[rB * 64 + ((g ^ (rB & 7)) * 8)];
      }
#pragma unroll
    for (int ks = 0; ks < 2; ++ks)
#pragma unroll
      for (int mi = 0; mi < 4; ++mi)
#pragma unroll
        for (int ni = 0; ni < 4; ++ni)
          acc[mi][ni] = MFMA16(af[mi][ks], bfr[ni][ks], acc[mi][ni]);
    __syncthreads();
  }

  const int rb = (lane >> 4) * 4, cb = lane & 15;
#pragma unroll
  for (int mi = 0; mi < 4; ++mi)
#pragma unroll
    for (int ni = 0; ni < 4; ++ni) {
      int r0 = bm + wr + mi * 16 + rb, c0 = bn + wc + ni * 16 + cb;
#pragma unroll
      for (int k = 0; k < 4; ++k)
        C[(long)(r0 + k) * DEMB + c0] = __float2bfloat16(acc[mi][ni][k]);
    }
}

// ---- merged F-GEMM + V-projection (one launch; V overlaps F) ----
// Slots [0, 256*G): F[m][n] = sum_c M[m][c]·Htb[n][c] (bf16) + column stats
// Slots [256*G, 288*G): Vb[z][e][n] = WV . Htb[z]^T
__global__ __launch_bounds__(256) void k_fv(
    const bf16* __restrict__ M0, const bf16* __restrict__ WV,
    const bf16* __restrict__ Htb0, bf16* __restrict__ F, bf16* __restrict__ Vb0,
    float* __restrict__ PMo, float* __restrict__ PSo, int G) {
  __shared__ __align__(16) bf16 sA[128 * 64];
  __shared__ __align__(16) bf16 sB[128 * 64];
  __shared__ float smx[4][64], ssx[4][64];
  const bf16 *A, *B;
  bf16* C;
  int ldC, bm, bn, by, bz;
  bool isF;
  {
    int s = blockIdx.x;
    isF = s < 256 * G;
    if (isF) {
      bz = s % G;
      int t = s / G;
      int bx = t & 15;
      by = t >> 4;
      A = M0 + (long)bz * STRD;
      B = Htb0 + (long)bz * STRD;
      C = F + (long)bz * NN; ldC = NPT;
      bm = by * 128; bn = bx * 128;
    } else {
      int s2 = s - 256 * G;
      bz = s2 % G;
      int t = s2 / G;
      A = WV;
      B = Htb0 + (long)bz * STRD;
      C = Vb0 + (long)bz * STRD; ldC = NPT;
      bm = (t >> 4) * 128; bn = (t & 15) * 128;
      by = 0;
    }
  }
  const int tid = threadIdx.x;
  const int lane = tid & 63, wv = tid >> 6;
  const int wr = (wv >> 1) * 64, wc = (wv & 1) * 64;
  f32x4 acc[4][4] = {};

  for (int k0 = 0; k0 < DEMB; k0 += 64) {
#pragma unroll
    for (int i = 0; i < 4; ++i) {
      int c = i * 256 + tid;
      int row = c >> 3, g = c & 7;
      int gs = (g ^ (row & 7)) * 8;
      gload16(A + (long)(bm + row) * DEMB + k0 + gs, sA + c * 8);
      gload16(B + (long)(bn + row) * DEMB + k0 + gs, sB + c * 8);
    }
    __syncthreads();
    bf16x8v af[4][2], bfr[4][2];
#pragma unroll
    for (int mi = 0; mi < 4; ++mi)
#pragma unroll
      for (int ks = 0; ks < 2; ++ks) {
        int rA = wr + mi * 16 + (lane & 15);
        int rB = wc + mi * 16 + (lane & 15);
        int g = ks * 4 + (lane >> 4);
        af[mi][ks]  = *(const bf16x8v*)&sA[rA * 64 + ((g ^ (rA & 7)) * 8)];
        bfr[mi][ks] = *(const bf16x8v*)&sB[rB * 64 + ((g ^ (rB & 7)) * 8)];
      }
#pragma unroll
    for (int ks = 0; ks < 2; ++ks)
#pragma unroll
      for (int mi = 0; mi < 4; ++mi)
#pragma unroll
        for (int ni = 0; ni < 4; ++ni)
          acc[mi][ni] = MFMA16(af[mi][ks], bfr[ni][ks], acc[mi][ni]);
    __syncthreads();
  }

  const int rb = (lane >> 4) * 4, cb = lane & 15;
#pragma unroll
  for (int mi = 0; mi < 4; ++mi)
#pragma unroll
    for (int ni = 0; ni < 4; ++ni) {
      int r0 = bm + wr + mi * 16 + rb, c0 = bn + wc + ni * 16 + cb;
#pragma unroll
      for (int k = 0; k < 4; ++k)
        C[(long)(r0 + k) * ldC + c0] = __float2bfloat16(acc[mi][ni][k]);
    }

  if (isF) {
    // per-column (over this block's 128 rows) online-softmax partials
    float cm[4], cs[4];
#pragma unroll
    for (int ni = 0; ni < 4; ++ni) {
      float m = -3.0e38f;
#pragma unroll
      for (int mi = 0; mi < 4; ++mi)
#pragma unroll
        for (int k = 0; k < 4; ++k) m = fmaxf(m, acc[mi][ni][k]);
      float s = 0.f;
#pragma unroll
      for (int mi = 0; mi < 4; ++mi)
#pragma unroll
        for (int k = 0; k < 4; ++k) s += __expf(acc[mi][ni][k] - m);
#pragma unroll
      for (int off = 16; off <= 32; off <<= 1) {
        float mo = __shfl_xor(m, off, 64);
        float so = __shfl_xor(s, off, 64);
        float M2 = fmaxf(m, mo);
        s = s * __expf(m - M2) + so * __expf(mo - M2);
        m = M2;
      }
      cm[ni] = m; cs[ni] = s;
    }
    __syncthreads();
    if (lane < 16) {
#pragma unroll
      for (int ni = 0; ni < 4; ++ni) {
        smx[wv][ni * 16 + lane] = cm[ni];
        ssx[wv][ni * 16 + lane] = cs[ni];
      }
    }
    __syncthreads();
    if (tid < 128) {
      int half = tid >> 6, c64 = tid & 63;
      float m1 = smx[half][c64], s1 = ssx[half][c64];
      float m2 = smx[half + 2][c64], s2 = ssx[half + 2][c64];
      float M2 = fmaxf(m1, m2);
      float S = s1 * __expf(m1 - M2) + s2 * __expf(m2 - M2);
      long o = ((long)bz * 16 + by) * NPT + bn + half * 64 + c64;
      PMo[o] = M2;
      PSo[o] = S;
    }
  }
}

// ---- fused colstat-combine + normalize + rowsum + V.P GEMM ----
// wHtb=1: Hn += delta, Htb = bf16(Hn). wHtb=0 (last layer): no Hn/Htb
// writes; instead POOL[z*NPT + m] = rowmean_e(Hn + delta).
__global__ __launch_bounds__(512) void k_vp(const bf16* __restrict__ F,
                                            const float* __restrict__ PM,
                                            const float* __restrict__ PSm,
                                            const bf16* __restrict__ V,
                                            float* __restrict__ Hn,
                                            bf16* __restrict__ Htb,
                                            float* __restrict__ POOL, int nz, int wHtb) {
  __shared__ __align__(16) bf16 sA[2][256 * 64];
  __shared__ __align__(16) bf16 sB[2][64 * 64];
  __shared__ float rsLds[64][8];
  __shared__ float Sv[64];
  __shared__ float psum[8][32];
  __shared__ float smCM[NPT], smCS[NPT];
  const int z = blockIdx.x % nz;
  const int m0 = (blockIdx.x / nz) * 64;
  const int tid = threadIdx.x;
  const int lane = tid & 63, wv = tid >> 6;
  const int we = wv & 3;
  const int wm = wv >> 2;
  const int fr = tid >> 3;
  const int fq = tid & 7;
  const bf16* Vz = V + (long)z * STRD;
  const bf16* Frp = F + (long)z * NN + (long)(m0 + fr) * NPT + fq * 8;
  f32x4 acc[4][2] = {};
  float rs = 0.f;
  bf16x8v fvA, fvB;

  {
    const float* pm = PM + (long)z * 16 * NPT;
    const float* ps = PSm + (long)z * 16 * NPT;
#pragma unroll
    for (int i = 0; i < 4; ++i) {
      int n = i * 512 + tid;
      float m = -3.0e38f;
#pragma unroll
      for (int y = 0; y < 16; ++y) m = fmaxf(m, pm[(long)y * NPT + n]);
      float s = 0.f;
#pragma unroll
      for (int y = 0; y < 16; ++y) s += ps[(long)y * NPT + n] * __expf(pm[(long)y * NPT + n] - m);
      smCM[n] = m;
      smCS[n] = 1.0f / s;
    }
  }

#define LOADF(FREG, N0) FREG = *(const bf16x8v*)(Frp + ((N0) & 2047));

#define EXPW(BUF, FREG, N0)                                                    \
  {                                                                            \
    float mv[8], cv[8];                                                        \
    *(float4*)&mv[0] = *(const float4*)&smCM[(N0) + fq * 8];                   \
    *(float4*)&mv[4] = *(const float4*)&smCM[(N0) + fq * 8 + 4];               \
    *(float4*)&cv[0] = *(const float4*)&smCS[(N0) + fq * 8];                   \
    *(float4*)&cv[4] = *(const float4*)&smCS[(N0) + fq * 8 + 4];               \
    bf16 tb[8];                                                                \
    _Pragma("unroll") for (int i = 0; i < 8; ++i) {                            \
      float fvi = __uint_as_float((unsigned)(unsigned short)FREG[i] << 16);    \
      float pv = __expf(fvi - mv[i]) * cv[i];                                  \
      rs += pv;                                                                \
      tb[i] = __float2bfloat16(pv);                                            \
    }                                                                          \
    *(bf16x8v*)&sB[BUF][fr * 64 + ((fq ^ (fr & 7)) * 8)] = *(bf16x8v*)tb;      \
  }

#define STAGEV(BUF, N0)                                                        \
  _Pragma("unroll") for (int i = 0; i < 4; ++i) {                              \
    int c = i * 512 + tid;                                                     \
    int row = c >> 3, g = c & 7;                                               \
    gload16(Vz + (long)row * NPT + ((N0) & 2047) + ((g ^ (row & 7)) * 8),      \
            &sA[BUF][c * 8]);                                                  \
  }

#define WAITBAR                                                                \
  asm volatile("s_waitcnt vmcnt(1) lgkmcnt(0)" ::: "memory");                  \
  __builtin_amdgcn_s_barrier();

  LOADF(fvA, 0)
  STAGEV(0, 0)
  __syncthreads();
  EXPW(0, fvA, 0)
  LOADF(fvB, 64)
  __syncthreads();

#define VP_BODY(CUR, FN, FN2, STEPI)                                           \
  {                                                                            \
    const int sn = (STEPI);                                                    \
    const int nn0 = sn * 64;                                                   \
    STAGEV(CUR ^ 1, nn0 + 64)                                                  \
    LOADF(FN2, nn0 + 128)                                                      \
    if (sn + 1 < 32) EXPW(CUR ^ 1, FN, nn0 + 64)                               \
    bf16x8v bfr[2][2];                                                         \
    _Pragma("unroll") for (int ni = 0; ni < 2; ++ni)                           \
      _Pragma("unroll") for (int ks = 0; ks < 2; ++ks) {                       \
        int rB = wm * 32 + ni * 16 + (lane & 15);                              \
        int g = ks * 4 + (lane >> 4);                                          \
        bfr[ni][ks] = *(const bf16x8v*)&sB[CUR][rB * 64 + ((g ^ (rB & 7)) * 8)]; \
      }                                                                        \
    _Pragma("unroll") for (int mi = 0; mi < 4; ++mi)                           \
      _Pragma("unroll") for (int ks = 0; ks < 2; ++ks) {                       \
        int rA = we * 64 + mi * 16 + (lane & 15);                              \
        int g = ks * 4 + (lane >> 4);                                          \
        bf16x8v af = *(const bf16x8v*)&sA[CUR][rA * 64 + ((g ^ (rA & 7)) * 8)]; \
        _Pragma("unroll") for (int ni = 0; ni < 2; ++ni)                       \
          acc[mi][ni] = MFMA16(af, bfr[ni][ks], acc[mi][ni]);                  \
      }                                                                        \
    WAITBAR                                                                    \
  }

  for (int it = 0; it < 16; ++it) {
    VP_BODY(0, fvB, fvA, 2 * it)
    VP_BODY(1, fvA, fvB, 2 * it + 1)
  }
#undef VP_BODY
#undef WAITBAR
#undef STAGEV
#undef EXPW
#undef LOADF

  rsLds[fr][fq] = rs;
  __syncthreads();
  if (tid < 64) {
    float R = 0.f;
#pragma unroll
    for (int q = 0; q < 8; ++q) R += rsLds[tid][q];
    Sv[tid] = 1.0f / (1e-9f + R);
  }
  __syncthreads();

  float* Hz = Hn + (long)z * STRD;
  bf16* Hb = Htb + (long)z * STRD;
  const int rb = (lane >> 4) * 4, cb = lane & 15;
  float csum[2] = {0.f, 0.f};
#pragma unroll
  for (int mi = 0; mi < 4; ++mi) {
    int e0 = we * 64 + mi * 16 + rb;
#pragma unroll
    for (int ni = 0; ni < 2; ++ni) {
      int c = wm * 32 + ni * 16 + cb;
      float scl = Sv[c];
      long base = (long)(m0 + c) * DEMB + e0;
      float4 h = *(const float4*)(Hz + base);
      float r0 = h.x + acc[mi][ni][0] * scl;
      float r1 = h.y + acc[mi][ni][1] * scl;
      float r2 = h.z + acc[mi][ni][2] * scl;
      float r3 = h.w + acc[mi][ni][3] * scl;
      if (wHtb) {
        *(float4*)(Hz + base) = float4{r0, r1, r2, r3};
        bf16 hb[4] = {__float2bfloat16(r0), __float2bfloat16(r1),
                      __float2bfloat16(r2), __float2bfloat16(r3)};
        *(uint2*)(Hb + base) = *(uint2*)hb;
      }
      csum[ni] += (r0 + r1) + (r2 + r3);
    }
  }

  if (!wHtb) {
#pragma unroll
    for (int ni = 0; ni < 2; ++ni) {
      float s = csum[ni];
      s += __shfl_down(s, 16, 64);
      s += __shfl_down(s, 32, 64);
      if (lane < 16) psum[wv][ni * 16 + lane] = s;
    }
    __syncthreads();
    if (tid < 64) {
      int wmq = tid >> 5, cl = tid & 31;
      float s = psum[wmq * 4 + 0][cl] + psum[wmq * 4 + 1][cl] +
                psum[wmq * 4 + 2][cl] + psum[wmq * 4 + 3][cl];
      POOL[(long)z * NPT + m0 + wmq * 32 + cl] = s * (1.0f / DEMB);
    }
  }
}

// ---- fc1: one block per output row j; w row read ONCE, all 8 batches ----
__global__ __launch_bounds__(256) void k_fc1(const float* __restrict__ pooled,
                                             const float* __restrict__ w, const float* __restrict__ bias,
                                             float* __restrict__ f) {
  int j = blockIdx.x;
  const float* wr = w + (long)j * NPT;
  int n0 = threadIdx.x * 8;
  float wl[8];
  *(float4*)&wl[0] = *(const float4*)(wr + n0);
  *(float4*)&wl[4] = *(const float4*)(wr + n0 + 4);
  float part[8];
#pragma unroll
  for (int b = 0; b < 8; ++b) {
    const float* pp = pooled + (long)b * NPT + n0;
    float4 p0 = *(const float4*)pp, p1 = *(const float4*)(pp + 4);
    part[b] = wl[0] * p0.x + wl[1] * p0.y + wl[2] * p0.z + wl[3] * p0.w +
              wl[4] * p1.x + wl[5] * p1.y + wl[6] * p1.z + wl[7] * p1.w;
  }
#pragma unroll
  for (int b = 0; b < 8; ++b) {
    float s = blockReduceSum(part[b]);
    if (threadIdx.x == 0) {
      s += bias[j];
      f[(long)b * NPT + j] = s > 0.f ? s : 0.f;
    }
  }
}

// ---- fc2 ----
__global__ __launch_bounds__(256) void k_fc2(const float* __restrict__ f,
                                             const float* __restrict__ w, const float* __restrict__ bias,
                                             float* __restrict__ out) {
  int b = blockIdx.x;
  float s = 0.f;
  for (int j = threadIdx.x; j < NPT; j += 256) s += f[(long)b * NPT + j] * w[j];
  s = blockReduceSum(s);
  if (threadIdx.x == 0) out[b] = s + bias[0];
}

extern "C" void kernel_launch(void* const* d_in, const int* in_sizes, int n_in,
                              void* d_out, int out_size, void* d_ws, size_t ws_size,
                              hipStream_t stream) {
  const float* X    = (const float*)d_in[0];
  const float* W1   = (const float*)d_in[1];
  const float* B1   = (const float*)d_in[2];
  const float* G1   = (const float*)d_in[3];
  const float* BE1  = (const float*)d_in[4];
  const float* W2   = (const float*)d_in[5];
  const float* B2   = (const float*)d_in[6];
  const float* G2   = (const float*)d_in[7];
  const float* BE2  = (const float*)d_in[8];
  const float* WQ   = (const float*)d_in[9];
  const float* WK   = (const float*)d_in[10];
  const float* WV   = (const float*)d_in[11];
  const float* FC1W = (const float*)d_in[12];
  const float* FC1B = (const float*)d_in[13];
  const float* FC2W = (const float*)d_in[14];
  const float* FC2B = (const float*)d_in[15];
  float* OUT = (float*)d_out;

  // ---- workspace carve-out ----
  char* p = (char*)d_ws;
  auto alloc = [&](size_t bytes) -> char* {
    char* r = p;
    p += (bytes + 255) & ~(size_t)255;
    return r;
  };
  float* H1t  = (float*)alloc((size_t)BATCH * NPT * DMID * 4);
  bf16*  H1tb = (bf16*)alloc((size_t)BATCH * NPT * DMID * 2);
  float* Hn   = (float*)alloc((size_t)BATCH * STRD * 4);   // [b*n][256] f32
  bf16*  Htb  = (bf16*)alloc((size_t)BATCH * STRD * 2);    // [b*n][256] bf16
  bf16*  Mb   = (bf16*)alloc((size_t)BATCH * STRD * 2);    // [b][n][256]
  bf16*  Vb   = (bf16*)alloc((size_t)BATCH * STRD * 2);    // [b][e][n]
  bf16*  W2b  = (bf16*)alloc((size_t)DEMB * DMID * 2);
  bf16*  WkqT = (bf16*)alloc((size_t)NSA * DEMB * DEMB * 2);
  bf16*  WVb  = (bf16*)alloc((size_t)NSA * DEMB * DEMB * 2);
  float* pS   = (float*)alloc(128 * 64 * 4);
  float* pS2  = (float*)alloc(128 * 64 * 4);
  float* pA2  = (float*)alloc(128 * DEMB * 4);
  float* pB2  = (float*)alloc(128 * DEMB * 4);
  float* sa1  = (float*)alloc(64 * 4);
  float* sb1  = (float*)alloc(64 * 4);
  float* sa2  = (float*)alloc(256 * 4);
  float* sb2  = (float*)alloc(256 * 4);
  float* PM   = (float*)alloc((size_t)BATCH * 16 * NPT * 4);
  float* PSm  = (float*)alloc((size_t)BATCH * 16 * NPT * 4);
  float* POOL = (float*)alloc((size_t)BATCH * NPT * 4);
  float* FH   = (float*)alloc((size_t)BATCH * NPT * 4);
  size_t used = (size_t)(p - (char*)d_ws);
  const size_t per_g = (size_t)NN * 2;  // F bf16 (8MB per batch)
  int G = 8;
  while (G > 1 && used + (size_t)G * per_g + 1024 > ws_size) G >>= 1;
  bf16* F = (bf16*)alloc((size_t)G * NN * 2);

  // ---- weight preprocessing (two small launches) ----
  int ncv = DEMB * DMID + NSA * DEMB * DEMB;
  k_cvtall<<<(ncv + 255) / 256, 256, 0, stream>>>(W2, WV, W2b, WVb);
  k_wkq<<<dim3(256, NSA), 256, 0, stream>>>(WQ, WK, WkqT);

  // ---- conv1 (+fused BN1 partials) + BN1 combine/apply ----
  k_conv1bn<<<128, 256, 0, stream>>>(X, W1, B1, H1t, pS, pS2);
  k_bn1b<<<1, 64, 0, stream>>>(pS, pS2, G1, BE1, sa1, sb1);
  k_bn1apply<<<(int)((long)BATCH * NPT * DMID / 4 / 256), 256, 0, stream>>>(H1t, sa1, sb1, H1tb);

  // ---- conv2 (MFMA + fused BN2 partials) + BN2 combine/apply ----
  k_mgemm2<<<dim3(2, 128), 256, 0, stream>>>(H1tb, DMID, W2b, DMID, Hn, DEMB, DMID,
                                             B2, pA2, pB2);
  k_bn2b<<<1, 256, 0, stream>>>(pA2, pB2, G2, BE2, sa2, sb2);
  k_bnapply2<<<(int)(BATCH * STRD / 4 / 256), 256, 0, stream>>>(Hn, Htb, sa2, sb2);

  // ---- SA layers ----
  for (int l = 0; l < NSA; ++l) {
    // M = Htb . Wkq (K-projection folded into weights; 256 blocks)
    k_m<<<dim3(256), 256, 0, stream>>>(Htb, WkqT + (long)l * DEMB * DEMB, Mb);
    for (int b0 = 0; b0 < BATCH; b0 += G) {
      // F = M . Htb^T + column stats, with V-projection overlapped
      k_fv<<<dim3(288 * G), 256, 0, stream>>>(Mb + b0 * STRD,
                                              WVb + (long)l * DEMB * DEMB,
                                              Htb + b0 * STRD,
                                              F, Vb + b0 * STRD, PM, PSm, G);
      // Hn += S*(V.PT); Htb = bf16(Hn) (non-last); last layer: emit POOL only
      k_vp<<<dim3(32 * G), 512, 0, stream>>>(F, PM, PSm, Vb + b0 * STRD,
                                             Hn + b0 * STRD, Htb + b0 * STRD,
                                             POOL + b0 * NPT, G,
                                             (l < NSA - 1) ? 1 : 0);
    }
  }

  // ---- head ----
  k_fc1<<<NPT, 256, 0, stream>>>(POOL, FC1W, FC1B, FH);
  k_fc2<<<BATCH, 256, 0, stream>>>(FH, FC2W, FC2B, OUT);
}